// Round 1
// baseline (199.072 us; speedup 1.0000x reference)
//
#include <hip/hip_runtime.h>
#include <hip/hip_bf16.h>

#define Bb 4
#define Ss 512
#define Ff 256
#define Dd 128

typedef __attribute__((ext_vector_type(8))) short bf8_t;   // 8 bf16 (4 VGPRs)
typedef __attribute__((ext_vector_type(4))) float f32x4;   // MFMA accumulator

__device__ __forceinline__ short bfbits(float x) {
  union { __hip_bfloat16 b; short s; } u;
  u.b = __hip_bfloat16(x);
  return u.s;
}

// tanh(x) = 1 - 2/(exp2(x*2*log2(e)) + 1); exp2 -> v_exp_f32, rcp -> v_rcp_f32
__device__ __forceinline__ float fast_tanh(float x) {
  float e = exp2f(x * 2.8853900818f);
  return 1.0f - 2.0f * __builtin_amdgcn_rcpf(e + 1.0f);
}

__global__ __launch_bounds__(256) void selfatten_kernel(
    const float* __restrict__ hidden, const float* __restrict__ Ws,
    const float* __restrict__ vs, float* __restrict__ out)
{
  __shared__ short htile[64][264];   // 64 keys x 256 f (bf16), +8 pad -> conflict-free b128
  __shared__ float s_part[4][64];
  __shared__ float s_full[512];
  __shared__ float red[8];

  const int tid   = threadIdx.x;
  const int lane  = tid & 63;
  const int w     = tid >> 6;     // wave 0..3, owns d-slice [w*32, w*32+32)
  const int col16 = lane & 15;
  const int grp   = lane >> 4;

  const int bq = blockIdx.x;
  const int b  = bq >> 9;
  const int q  = bq & 511;

  const float* Hb = hidden + (size_t)b * Ss * Ff;
  const float* hq = Hb + (size_t)q * Ff;

  // ---- Build A fragments in registers: A[d][f] = bf16(h_q[f] * Ws[d][f]) ----
  // A-frag layout: row d = (w*32 + mf*16 + col16), k-slot (grp, j) <- f = ks*32 + grp*8 + j
  bf8_t afr[2][8];
  #pragma unroll
  for (int ks = 0; ks < 8; ++ks) {
    const int f0 = ks * 32 + grp * 8;
    const float4 h0 = *(const float4*)(hq + f0);
    const float4 h1 = *(const float4*)(hq + f0 + 4);
    #pragma unroll
    for (int mf = 0; mf < 2; ++mf) {
      const int d = w * 32 + mf * 16 + col16;
      const float* wr = Ws + d * Ff + f0;
      const float4 w0 = *(const float4*)(wr);
      const float4 w1 = *(const float4*)(wr + 4);
      bf8_t t;
      t[0] = bfbits(h0.x * w0.x); t[1] = bfbits(h0.y * w0.y);
      t[2] = bfbits(h0.z * w0.z); t[3] = bfbits(h0.w * w0.w);
      t[4] = bfbits(h1.x * w1.x); t[5] = bfbits(h1.y * w1.y);
      t[6] = bfbits(h1.z * w1.z); t[7] = bfbits(h1.w * w1.w);
      afr[mf][ks] = t;
    }
  }

  // vs values matching the C/D row mapping: d = w*32 + mf*16 + 4*grp + r
  float vsv[2][4];
  #pragma unroll
  for (int mf = 0; mf < 2; ++mf)
    #pragma unroll
    for (int r = 0; r < 4; ++r)
      vsv[mf][r] = vs[w * 32 + mf * 16 + grp * 4 + r];

  // ---- Loop over key chunks of 64 ----
  for (int c = 0; c < 8; ++c) {
    const int k0 = c * 64;
    __syncthreads();  // protect htile + s_part reuse
    // stage H[b, k0:k0+64, :] as bf16 into LDS (contiguous 64KB f32 source)
    const float* src = Hb + (size_t)k0 * Ff;
    #pragma unroll
    for (int it = 0; it < 16; ++it) {
      const int lin = it * 1024 + tid * 4;
      const float4 v = *(const float4*)(src + lin);
      const int row = lin >> 8;
      const int col = lin & 255;
      short4 o = make_short4(bfbits(v.x), bfbits(v.y), bfbits(v.z), bfbits(v.w));
      *(short4*)(&htile[row][col]) = o;
    }
    __syncthreads();

    // GEMM: t[d, key] for this wave's 32 d x 64 keys, K = 256
    f32x4 acc[2][4] = {};
    #pragma unroll
    for (int nf = 0; nf < 4; ++nf) {
      #pragma unroll
      for (int ks = 0; ks < 8; ++ks) {
        // B-frag: B[f][key]: key = nf*16 + col16, k-slot (grp,j) <- f = ks*32 + grp*8 + j
        const bf8_t bb = *(const bf8_t*)(&htile[nf * 16 + col16][ks * 32 + grp * 8]);
        acc[0][nf] = __builtin_amdgcn_mfma_f32_16x16x32_bf16(afr[0][ks], bb, acc[0][nf], 0, 0, 0);
        acc[1][nf] = __builtin_amdgcn_mfma_f32_16x16x32_bf16(afr[1][ks], bb, acc[1][nf], 0, 0, 0);
      }
    }

    // reduce over this wave's 32 d: s_partial[key] = sum_d vs[d]*tanh(t[d,key])
    #pragma unroll
    for (int nf = 0; nf < 4; ++nf) {
      float ps = 0.f;
      #pragma unroll
      for (int mf = 0; mf < 2; ++mf)
        #pragma unroll
        for (int r = 0; r < 4; ++r)
          ps += vsv[mf][r] * fast_tanh(acc[mf][nf][r]);
      // lanes 16 apart share the same key column -> sum the 4 grp groups
      ps += __shfl_xor(ps, 16);
      ps += __shfl_xor(ps, 32);
      if (lane < 16) s_part[w][nf * 16 + lane] = ps;
    }
    __syncthreads();
    if (tid < 64)
      s_full[k0 + tid] = s_part[0][tid] + s_part[1][tid] + s_part[2][tid] + s_part[3][tid];
  }
  __syncthreads();

  // ---- softmax over 512 keys ----
  const float s0 = s_full[tid], s1 = s_full[tid + 256];
  float m = fmaxf(s0, s1);
  #pragma unroll
  for (int d = 1; d < 64; d <<= 1) m = fmaxf(m, __shfl_xor(m, d));
  if (lane == 0) red[w] = m;
  __syncthreads();
  m = fmaxf(fmaxf(red[0], red[1]), fmaxf(red[2], red[3]));
  const float p0 = exp2f((s0 - m) * 1.44269504f);
  const float p1 = exp2f((s1 - m) * 1.44269504f);
  float sm = p0 + p1;
  #pragma unroll
  for (int d = 1; d < 64; d <<= 1) sm += __shfl_xor(sm, d);
  if (lane == 0) red[4 + w] = sm;
  __syncthreads();
  const float tot = red[4] + red[5] + red[6] + red[7];
  const float inv = 1.0f / tot;
  const float a0 = p0 * inv, a1 = p1 * inv;
  float* att_out = out + (size_t)Bb * Ss * Ff + (size_t)bq * Ss;
  att_out[tid]       = a0;
  att_out[tid + 256] = a1;
  __syncthreads();              // all s_full reads (top of softmax) are done
  s_full[tid]       = a0;
  s_full[tid + 256] = a1;
  __syncthreads();

  // ---- context[q, f] = sum_k atten[k] * H[b, k, f], f = tid (coalesced rows) ----
  float ctx = 0.f;
  const float* hp = Hb + tid;
  #pragma unroll 8
  for (int k = 0; k < Ss; ++k)
    ctx += s_full[k] * hp[(size_t)k * Ff];
  out[(size_t)bq * Ff + tid] = ctx;
}

extern "C" void kernel_launch(void* const* d_in, const int* in_sizes, int n_in,
                              void* d_out, int out_size, void* d_ws, size_t ws_size,
                              hipStream_t stream) {
  (void)in_sizes; (void)n_in; (void)d_ws; (void)ws_size; (void)out_size;
  const float* hidden = (const float*)d_in[0];
  const float* Ws     = (const float*)d_in[1];
  const float* vs     = (const float*)d_in[2];
  float* out          = (float*)d_out;
  selfatten_kernel<<<dim3(Bb * Ss), dim3(256), 0, stream>>>(hidden, Ws, vs, out);
}

// Round 2
// 116.184 us; speedup vs baseline: 1.7134x; 1.7134x over previous
//
#include <hip/hip_runtime.h>
#include <hip/hip_bf16.h>

#define Bb 4
#define Ss 512
#define Ff 256
#define Dd 128
#define Gq 2

typedef __attribute__((ext_vector_type(8))) short bf8_t;   // 8 bf16 / 8 shorts
typedef __attribute__((ext_vector_type(4))) float f32x4;   // MFMA accumulator

__device__ __forceinline__ short bfbits(float x) {
  union { __hip_bfloat16 b; short s; } u;
  u.b = __hip_bfloat16(x);
  return u.s;
}

// tanh(x) = 1 - 2/(exp2(2x*log2e) + 1)
__device__ __forceinline__ float fast_tanh(float x) {
  float e = exp2f(x * 2.8853900818f);
  return 1.0f - 2.0f * __builtin_amdgcn_rcpf(e + 1.0f);
}

__global__ __launch_bounds__(256) void selfatten_kernel(
    const float* __restrict__ hidden, const float* __restrict__ Ws,
    const float* __restrict__ vs, float* __restrict__ out)
{
  __shared__ __align__(16) short htile[2][64][264]; // 66 KiB double-buffered key tile (bf16)
  __shared__ float s_part[2][4][2][64];             // [chunk-parity][wave][g][key]
  __shared__ float s_full[2][512];                  // [g][key] scores -> probs
  __shared__ float red[8];

  const int tid   = threadIdx.x;
  const int lane  = tid & 63;
  const int w     = tid >> 6;     // wave 0..3, owns d-slice [w*32, w*32+32)
  const int col16 = lane & 15;
  const int grp   = lane >> 4;

  const int blk = blockIdx.x;
  const int b   = blk >> 8;             // 256 q-pairs per batch
  const int q0  = (blk & 255) * Gq;

  const float* Hb = hidden + (size_t)b * Ss * Ff;

  // ---- A fragments for both queries: A[d][f] = bf16(h_q[f] * Ws[d][f]) ----
  // A-frag layout: row d = w*32 + mf*16 + col16, k-slot (grp,j) <- f = ks*32 + grp*8 + j
  bf8_t afr[Gq][2][8];
  #pragma unroll
  for (int ks = 0; ks < 8; ++ks) {
    const int f0 = ks * 32 + grp * 8;
    #pragma unroll
    for (int mf = 0; mf < 2; ++mf) {
      const int d = w * 32 + mf * 16 + col16;
      const float* wr = Ws + d * Ff + f0;
      const float4 w0 = *(const float4*)(wr);
      const float4 w1 = *(const float4*)(wr + 4);
      #pragma unroll
      for (int g = 0; g < Gq; ++g) {
        const float* hq = Hb + (size_t)(q0 + g) * Ff + f0;
        const float4 h0 = *(const float4*)(hq);
        const float4 h1 = *(const float4*)(hq + 4);
        bf8_t t;
        t[0] = bfbits(h0.x * w0.x); t[1] = bfbits(h0.y * w0.y);
        t[2] = bfbits(h0.z * w0.z); t[3] = bfbits(h0.w * w0.w);
        t[4] = bfbits(h1.x * w1.x); t[5] = bfbits(h1.y * w1.y);
        t[6] = bfbits(h1.z * w1.z); t[7] = bfbits(h1.w * w1.w);
        afr[g][mf][ks] = t;
      }
    }
  }

  // vs values matching C/D row map: d = w*32 + mf*16 + grp*4 + r
  float vsv[2][4];
  #pragma unroll
  for (int mf = 0; mf < 2; ++mf)
    #pragma unroll
    for (int r = 0; r < 4; ++r)
      vsv[mf][r] = vs[w * 32 + mf * 16 + grp * 4 + r];

  // ---- prologue: stage chunk 0 (rows 0..63) as bf16, 16B conflict-free writes ----
  #pragma unroll
  for (int it = 0; it < 8; ++it) {
    const int lin = it * 2048 + tid * 8;
    const float4 v0 = *(const float4*)(Hb + lin);
    const float4 v1 = *(const float4*)(Hb + lin + 4);
    const int row = lin >> 8, col = lin & 255;
    bf8_t o;
    o[0] = bfbits(v0.x); o[1] = bfbits(v0.y); o[2] = bfbits(v0.z); o[3] = bfbits(v0.w);
    o[4] = bfbits(v1.x); o[5] = bfbits(v1.y); o[6] = bfbits(v1.z); o[7] = bfbits(v1.w);
    *(bf8_t*)(&htile[0][row][col]) = o;
  }
  __syncthreads();

  // ---- main loop over 8 key chunks, double-buffered ----
  int cur = 0;
  for (int c = 0; c < 8; ++c) {
    const int k0  = c * 64;
    const int nxt = cur ^ 1;
    const int cb  = c & 1;
    const float* src = Hb + (size_t)(k0 + 64) * Ff;  // chunk c+1 source

    #pragma unroll
    for (int nf = 0; nf < 4; ++nf) {
      // issue next-chunk staging loads early (overlap with MFMA below)
      float4 sv[4];
      if (c < 7) {
        #pragma unroll
        for (int i = 0; i < 2; ++i) {
          const int lin = (nf * 2 + i) * 2048 + tid * 8;
          sv[2 * i]     = *(const float4*)(src + lin);
          sv[2 * i + 1] = *(const float4*)(src + lin + 4);
        }
      }

      // GEMM column nf: keys nf*16+col16, K=256
      f32x4 acc[Gq][2] = {};
      #pragma unroll
      for (int ks = 0; ks < 8; ++ks) {
        const bf8_t bbv = *(const bf8_t*)(&htile[cur][nf * 16 + col16][ks * 32 + grp * 8]);
        #pragma unroll
        for (int g = 0; g < Gq; ++g) {
          acc[g][0] = __builtin_amdgcn_mfma_f32_16x16x32_bf16(afr[g][0][ks], bbv, acc[g][0], 0, 0, 0);
          acc[g][1] = __builtin_amdgcn_mfma_f32_16x16x32_bf16(afr[g][1][ks], bbv, acc[g][1], 0, 0, 0);
        }
      }

      // reduce over this wave's 32 d
      #pragma unroll
      for (int g = 0; g < Gq; ++g) {
        float ps = 0.f;
        #pragma unroll
        for (int mf = 0; mf < 2; ++mf)
          #pragma unroll
          for (int r = 0; r < 4; ++r)
            ps += vsv[mf][r] * fast_tanh(acc[g][mf][r]);
        ps += __shfl_xor(ps, 16);
        ps += __shfl_xor(ps, 32);
        if (lane < 16) s_part[cb][w][g][nf * 16 + lane] = ps;
      }

      // complete staging for this nf slice (cvt + 16B write, conflict-free)
      if (c < 7) {
        #pragma unroll
        for (int i = 0; i < 2; ++i) {
          const int lin = (nf * 2 + i) * 2048 + tid * 8;
          const int row = lin >> 8, col = lin & 255;
          const float4 a = sv[2 * i], bsv = sv[2 * i + 1];
          bf8_t o;
          o[0] = bfbits(a.x); o[1] = bfbits(a.y); o[2] = bfbits(a.z); o[3] = bfbits(a.w);
          o[4] = bfbits(bsv.x); o[5] = bfbits(bsv.y); o[6] = bfbits(bsv.z); o[7] = bfbits(bsv.w);
          *(bf8_t*)(&htile[nxt][row][col]) = o;
        }
      }
    }
    __syncthreads();
    if (tid < 128) {
      const int g = tid >> 6, key = tid & 63;
      s_full[g][k0 + key] = s_part[cb][0][g][key] + s_part[cb][1][g][key] +
                            s_part[cb][2][g][key] + s_part[cb][3][g][key];
    }
    cur = nxt;
  }
  __syncthreads();

  // ---- softmax per query ----
  float av[Gq][2];
  #pragma unroll
  for (int g = 0; g < Gq; ++g) {
    const float s0 = s_full[g][tid], s1 = s_full[g][tid + 256];
    float m = fmaxf(s0, s1);
    #pragma unroll
    for (int d = 1; d < 64; d <<= 1) m = fmaxf(m, __shfl_xor(m, d));
    if (lane == 0) red[w] = m;
    __syncthreads();
    m = fmaxf(fmaxf(red[0], red[1]), fmaxf(red[2], red[3]));
    const float p0 = exp2f((s0 - m) * 1.44269504f);
    const float p1 = exp2f((s1 - m) * 1.44269504f);
    float sm = p0 + p1;
    #pragma unroll
    for (int d = 1; d < 64; d <<= 1) sm += __shfl_xor(sm, d);
    if (lane == 0) red[4 + w] = sm;
    __syncthreads();
    const float inv = 1.0f / (red[4] + red[5] + red[6] + red[7]);
    av[g][0] = p0 * inv; av[g][1] = p1 * inv;
    float* att = out + (size_t)Bb * Ss * Ff + ((size_t)(b * Ss + q0 + g)) * Ss;
    att[tid]       = av[g][0];
    att[tid + 256] = av[g][1];
    __syncthreads();   // red reuse + (last iter) s_full reads all done
  }
  s_full[0][tid] = av[0][0]; s_full[0][tid + 256] = av[0][1];
  s_full[1][tid] = av[1][0]; s_full[1][tid + 256] = av[1][1];
  __syncthreads();

  // ---- context: wave w owns k in [w*128, w*128+128); one H row load feeds both queries ----
  float* ctxp = (float*)htile;   // reuse: [4 waves][2 g][256 f]
  float4 c0 = {0.f, 0.f, 0.f, 0.f}, c1 = {0.f, 0.f, 0.f, 0.f};
  const float* hp = Hb + (size_t)(w * 128) * Ff + lane * 4;
  #pragma unroll 8
  for (int k = 0; k < 128; ++k) {
    const float4 h = *(const float4*)(hp + (size_t)k * Ff);
    const float a0 = s_full[0][w * 128 + k];
    const float a1 = s_full[1][w * 128 + k];
    c0.x += a0 * h.x; c0.y += a0 * h.y; c0.z += a0 * h.z; c0.w += a0 * h.w;
    c1.x += a1 * h.x; c1.y += a1 * h.y; c1.z += a1 * h.z; c1.w += a1 * h.w;
  }
  *(float4*)(&ctxp[(w * 2 + 0) * 256 + lane * 4]) = c0;
  *(float4*)(&ctxp[(w * 2 + 1) * 256 + lane * 4]) = c1;
  __syncthreads();
  #pragma unroll
  for (int rep = 0; rep < 2; ++rep) {
    const int idx = tid + rep * 256;
    const int g = idx >> 8, f = idx & 255;
    const float v = ctxp[(0 * 2 + g) * 256 + f] + ctxp[(1 * 2 + g) * 256 + f] +
                    ctxp[(2 * 2 + g) * 256 + f] + ctxp[(3 * 2 + g) * 256 + f];
    out[((size_t)(b * Ss) + q0 + g) * Ff + f] = v;
  }
}

extern "C" void kernel_launch(void* const* d_in, const int* in_sizes, int n_in,
                              void* d_out, int out_size, void* d_ws, size_t ws_size,
                              hipStream_t stream) {
  (void)in_sizes; (void)n_in; (void)d_ws; (void)ws_size; (void)out_size;
  const float* hidden = (const float*)d_in[0];
  const float* Ws     = (const float*)d_in[1];
  const float* vs     = (const float*)d_in[2];
  float* out          = (float*)d_out;
  selfatten_kernel<<<dim3(Bb * Ss / Gq), dim3(256), 0, stream>>>(hidden, Ws, vs, out);
}

// Round 3
// 85.119 us; speedup vs baseline: 2.3388x; 1.3650x over previous
//
#include <hip/hip_runtime.h>
#include <hip/hip_bf16.h>

#define Bb 4
#define Ss 512
#define Ff 256
#define Dd 128

typedef __attribute__((ext_vector_type(8))) short bf8_t;   // 8 bf16
typedef __attribute__((ext_vector_type(4))) float f32x4;   // MFMA accumulator

__device__ __forceinline__ short bfbits(float x) {
  union { __hip_bfloat16 b; short s; } u;
  u.b = __hip_bfloat16(x);
  return u.s;
}

// tanh(x) = 1 - 2/(exp2(2x*log2e)+1)
__device__ __forceinline__ float fast_tanh(float x) {
  float e = exp2f(x * 2.8853900818f);
  return 1.0f - 2.0f * __builtin_amdgcn_rcpf(e + 1.0f);
}

typedef __attribute__((address_space(3))) unsigned int lds_u32;
typedef const __attribute__((address_space(1))) unsigned int glb_u32;
__device__ __forceinline__ void load_lds16(const void* g, void* l) {
  __builtin_amdgcn_global_load_lds((glb_u32*)g, (lds_u32*)l, 16, 0, 0);
}

// ---------------- kernel 0: f32 -> bf16 convert with XOR row-swizzle --------
// hbf[r][c ^ ((r&7)<<3)] = bf16(H[r][c]); linear DMA of hbf then gives the
// swizzled LDS tile (2-way max bank aliasing on b128 reads/writes = free).
__global__ __launch_bounds__(256) void cvt_kernel(const float* __restrict__ hidden,
                                                  short* __restrict__ hbf) {
  const int idx = blockIdx.x * 256 + threadIdx.x;
  const int lin = idx * 4;
  const float4 v = *(const float4*)(hidden + lin);
  const int r = lin >> 8;
  const int c = lin & 255;
  const int cs = c ^ ((r & 7) << 3);   // 4-aligned block stays contiguous
  short4 o = make_short4(bfbits(v.x), bfbits(v.y), bfbits(v.z), bfbits(v.w));
  *(short4*)(hbf + ((size_t)r << 8) + cs) = o;
}

// ---------------- kernel 1: symmetric scores ------------------------------
// block = (pair, b); computes s[q,k] for q in {2p,2p+1}, k >= q0 only
// (exploits s[q,k]==s[k,q]); writes row strip + transpose strip to Sws.
__global__ __launch_bounds__(256) void score_kernel(
    const float* __restrict__ hidden, const short* __restrict__ hbf,
    const float* __restrict__ Ws, const float* __restrict__ vs,
    float* __restrict__ Sws)
{
  __shared__ __align__(16) short htile[2][64 * 256];  // 2 x 32KB, linear (pre-swizzled src)
  __shared__ float s_part[4][2][64];

  const int tid   = threadIdx.x;
  const int lane  = tid & 63;
  const int w     = tid >> 6;
  const int col16 = lane & 15;
  const int grp   = lane >> 4;

  const int blk  = blockIdx.x;
  const int pair = blk >> 2;          // ascending: longest blocks first (LPT)
  const int b    = blk & 3;
  const int q0   = pair * 2;
  const int c0   = q0 >> 6;

  const float* Hb  = hidden + (size_t)b * Ss * Ff;
  const short* hsb = hbf + (size_t)b * Ss * Ff;
  float*       Sb  = Sws + (size_t)b * Ss * Ss;

  // ---- A frags: A[d][f] = bf16(h_q[f]*Ws[d][f]); row d = w*32+mf*16+col16,
  //      k-slot (grp,j) <- f = ks*32+grp*8+j
  bf8_t afr[2][2][8];
  #pragma unroll
  for (int ks = 0; ks < 8; ++ks) {
    const int f0 = ks * 32 + grp * 8;
    float4 h0[2], h1[2];
    #pragma unroll
    for (int g = 0; g < 2; ++g) {
      const float* hq = Hb + (size_t)(q0 + g) * Ff + f0;
      h0[g] = *(const float4*)(hq);
      h1[g] = *(const float4*)(hq + 4);
    }
    #pragma unroll
    for (int mf = 0; mf < 2; ++mf) {
      const int d = w * 32 + mf * 16 + col16;
      const float* wr = Ws + (size_t)d * Ff + f0;
      const float4 w0 = *(const float4*)(wr);
      const float4 w1 = *(const float4*)(wr + 4);
      #pragma unroll
      for (int g = 0; g < 2; ++g) {
        bf8_t t;
        t[0] = bfbits(h0[g].x * w0.x); t[1] = bfbits(h0[g].y * w0.y);
        t[2] = bfbits(h0[g].z * w0.z); t[3] = bfbits(h0[g].w * w0.w);
        t[4] = bfbits(h1[g].x * w1.x); t[5] = bfbits(h1[g].y * w1.y);
        t[6] = bfbits(h1[g].z * w1.z); t[7] = bfbits(h1[g].w * w1.w);
        afr[g][mf][ks] = t;
      }
    }
  }

  // vs matching C/D row map: d = w*32 + mf*16 + grp*4 + r
  float vsv[2][4];
  #pragma unroll
  for (int mf = 0; mf < 2; ++mf)
    #pragma unroll
    for (int r = 0; r < 4; ++r)
      vsv[mf][r] = vs[w * 32 + mf * 16 + grp * 4 + r];

  // ---- prologue: DMA chunk c0 into buf 0 (8 x 16B per thread, pure DMA) ----
  {
    const short* src = hsb + c0 * (64 * 256);
    #pragma unroll
    for (int i = 0; i < 8; ++i) {
      const int seg = i * 4 + w;                     // 1KB segment per wave-issue
      load_lds16(src + seg * 512 + lane * 8, &htile[0][seg * 512]);
    }
  }

  const int swz = (col16 & 7) << 3;   // read-side XOR (matches cvt_kernel)

  int cur = 0;
  for (int c = c0; c < 8; ++c) {
    const int k0 = c << 6;
    __syncthreads();                  // drains vmcnt -> buf[cur] DMA complete
    if (c < 7) {                      // prefetch next chunk into other buffer
      const short* src = hsb + (c + 1) * (64 * 256);
      const int nb = cur ^ 1;
      #pragma unroll
      for (int i = 0; i < 8; ++i) {
        const int seg = i * 4 + w;
        load_lds16(src + seg * 512 + lane * 8, &htile[nb][seg * 512]);
      }
    }
    // compute on buf[cur]: 2q x 32d x 64k, K=256
    #pragma unroll
    for (int nf = 0; nf < 4; ++nf) {
      f32x4 acc[2][2] = {};
      const int rbase = nf * 4096 + col16 * 256;
      #pragma unroll
      for (int ks = 0; ks < 8; ++ks) {
        const int coff = (ks * 32 + grp * 8) ^ swz;
        const bf8_t bbv = *(const bf8_t*)(&htile[cur][rbase + coff]);
        acc[0][0] = __builtin_amdgcn_mfma_f32_16x16x32_bf16(afr[0][0][ks], bbv, acc[0][0], 0, 0, 0);
        acc[0][1] = __builtin_amdgcn_mfma_f32_16x16x32_bf16(afr[0][1][ks], bbv, acc[0][1], 0, 0, 0);
        acc[1][0] = __builtin_amdgcn_mfma_f32_16x16x32_bf16(afr[1][0][ks], bbv, acc[1][0], 0, 0, 0);
        acc[1][1] = __builtin_amdgcn_mfma_f32_16x16x32_bf16(afr[1][1][ks], bbv, acc[1][1], 0, 0, 0);
      }
      #pragma unroll
      for (int g = 0; g < 2; ++g) {
        float ps = 0.f;
        #pragma unroll
        for (int mf = 0; mf < 2; ++mf)
          #pragma unroll
          for (int r = 0; r < 4; ++r)
            ps += vsv[mf][r] * fast_tanh(acc[g][mf][r]);
        ps += __shfl_xor(ps, 16);
        ps += __shfl_xor(ps, 32);
        if (lane < 16) s_part[w][g][nf * 16 + lane] = ps;
      }
    }
    // mid barrier WITHOUT vmcnt drain: prefetch DMA stays in flight
    asm volatile("s_waitcnt lgkmcnt(0)" ::: "memory");
    __builtin_amdgcn_sched_barrier(0);
    __builtin_amdgcn_s_barrier();
    __builtin_amdgcn_sched_barrier(0);
    if (tid < 128) {
      const int g = tid >> 6, key = tid & 63;
      const int k = k0 + key;
      if (k >= q0) {
        const float v = s_part[0][g][key] + s_part[1][g][key] +
                        s_part[2][g][key] + s_part[3][g][key];
        Sb[(size_t)(q0 + g) * Ss + k] = v;                 // row strip
        if (k >= q0 + 2) Sb[(size_t)k * Ss + (q0 + g)] = v; // transpose strip
      }
    }
    cur ^= 1;
  }
}

// ---------------- kernel 2: softmax + context (4 queries / block) ----------
__global__ __launch_bounds__(256) void ctx_kernel(
    const float* __restrict__ hidden, const float* __restrict__ Sws,
    float* __restrict__ out)
{
  __shared__ float p[4][512];
  __shared__ float ctxp[4][4][256];   // [wave][g][f]
  __shared__ float red[8];

  const int tid = threadIdx.x, lane = tid & 63, w = tid >> 6;
  const int blk = blockIdx.x;
  const int b   = blk >> 7;
  const int q0  = (blk & 127) * 4;

  const float* Sb = Sws + (size_t)b * Ss * Ss;
  const float* Hb = hidden + (size_t)b * Ss * Ff;
  float* att = out + (size_t)Bb * Ss * Ff + ((size_t)(b * Ss + q0)) * Ss;

  #pragma unroll
  for (int g = 0; g < 4; ++g) {
    const float s0 = Sb[(size_t)(q0 + g) * Ss + tid];
    const float s1 = Sb[(size_t)(q0 + g) * Ss + tid + 256];
    float m = fmaxf(s0, s1);
    #pragma unroll
    for (int d = 1; d < 64; d <<= 1) m = fmaxf(m, __shfl_xor(m, d));
    if (lane == 0) red[w] = m;
    __syncthreads();
    m = fmaxf(fmaxf(red[0], red[1]), fmaxf(red[2], red[3]));
    const float p0 = exp2f((s0 - m) * 1.44269504f);
    const float p1 = exp2f((s1 - m) * 1.44269504f);
    float sm = p0 + p1;
    #pragma unroll
    for (int d = 1; d < 64; d <<= 1) sm += __shfl_xor(sm, d);
    if (lane == 0) red[4 + w] = sm;
    __syncthreads();
    const float inv = 1.0f / (red[4] + red[5] + red[6] + red[7]);
    const float a0 = p0 * inv, a1 = p1 * inv;
    att[(size_t)g * Ss + tid]       = a0;
    att[(size_t)g * Ss + tid + 256] = a1;
    p[g][tid] = a0; p[g][tid + 256] = a1;
  }
  __syncthreads();

  // context: wave w owns k in [w*128, w*128+128); one H row feeds 4 queries
  float4 cg[4] = {{0,0,0,0},{0,0,0,0},{0,0,0,0},{0,0,0,0}};
  const float* hp = Hb + (size_t)(w * 128) * Ff + lane * 4;
  #pragma unroll 4
  for (int k = 0; k < 128; ++k) {
    const float4 h = *(const float4*)(hp + (size_t)k * Ff);
    #pragma unroll
    for (int g = 0; g < 4; ++g) {
      const float a = p[g][w * 128 + k];
      cg[g].x += a * h.x; cg[g].y += a * h.y; cg[g].z += a * h.z; cg[g].w += a * h.w;
    }
  }
  #pragma unroll
  for (int g = 0; g < 4; ++g)
    *(float4*)(&ctxp[w][g][lane * 4]) = cg[g];
  __syncthreads();
  #pragma unroll
  for (int rep = 0; rep < 4; ++rep) {
    const int idx = rep * 256 + tid;
    const int g = idx >> 8, f = idx & 255;
    out[((size_t)(b * Ss) + q0 + g) * Ff + f] =
        ctxp[0][g][f] + ctxp[1][g][f] + ctxp[2][g][f] + ctxp[3][g][f];
  }
}

// ---------------- fallback (R2 kernel, no workspace needed) ----------------
__global__ __launch_bounds__(256) void selfatten_fallback(
    const float* __restrict__ hidden, const float* __restrict__ Ws,
    const float* __restrict__ vs, float* __restrict__ out)
{
  __shared__ __align__(16) short htile[2][64][264];
  __shared__ float s_part[2][4][2][64];
  __shared__ float s_full[2][512];
  __shared__ float red[8];

  const int tid = threadIdx.x, lane = tid & 63, w = tid >> 6;
  const int col16 = lane & 15, grp = lane >> 4;
  const int blk = blockIdx.x, b = blk >> 8, q0 = (blk & 255) * 2;
  const float* Hb = hidden + (size_t)b * Ss * Ff;

  bf8_t afr[2][2][8];
  #pragma unroll
  for (int ks = 0; ks < 8; ++ks) {
    const int f0 = ks * 32 + grp * 8;
    #pragma unroll
    for (int mf = 0; mf < 2; ++mf) {
      const int d = w * 32 + mf * 16 + col16;
      const float* wr = Ws + (size_t)d * Ff + f0;
      const float4 w0 = *(const float4*)(wr);
      const float4 w1 = *(const float4*)(wr + 4);
      #pragma unroll
      for (int g = 0; g < 2; ++g) {
        const float* hq = Hb + (size_t)(q0 + g) * Ff + f0;
        const float4 h0 = *(const float4*)(hq);
        const float4 h1 = *(const float4*)(hq + 4);
        bf8_t t;
        t[0] = bfbits(h0.x * w0.x); t[1] = bfbits(h0.y * w0.y);
        t[2] = bfbits(h0.z * w0.z); t[3] = bfbits(h0.w * w0.w);
        t[4] = bfbits(h1.x * w1.x); t[5] = bfbits(h1.y * w1.y);
        t[6] = bfbits(h1.z * w1.z); t[7] = bfbits(h1.w * w1.w);
        afr[g][mf][ks] = t;
      }
    }
  }
  float vsv[2][4];
  #pragma unroll
  for (int mf = 0; mf < 2; ++mf)
    #pragma unroll
    for (int r = 0; r < 4; ++r) vsv[mf][r] = vs[w * 32 + mf * 16 + grp * 4 + r];

  #pragma unroll
  for (int it = 0; it < 8; ++it) {
    const int lin = it * 2048 + tid * 8;
    const float4 v0 = *(const float4*)(Hb + lin);
    const float4 v1 = *(const float4*)(Hb + lin + 4);
    const int row = lin >> 8, col = lin & 255;
    bf8_t o;
    o[0] = bfbits(v0.x); o[1] = bfbits(v0.y); o[2] = bfbits(v0.z); o[3] = bfbits(v0.w);
    o[4] = bfbits(v1.x); o[5] = bfbits(v1.y); o[6] = bfbits(v1.z); o[7] = bfbits(v1.w);
    *(bf8_t*)(&htile[0][row][col]) = o;
  }
  __syncthreads();
  int cur = 0;
  for (int c = 0; c < 8; ++c) {
    const int k0 = c * 64, nxt = cur ^ 1, cb = c & 1;
    const float* src = Hb + (size_t)(k0 + 64) * Ff;
    #pragma unroll
    for (int nf = 0; nf < 4; ++nf) {
      float4 sv[4];
      if (c < 7) {
        #pragma unroll
        for (int i = 0; i < 2; ++i) {
          const int lin = (nf * 2 + i) * 2048 + tid * 8;
          sv[2 * i] = *(const float4*)(src + lin);
          sv[2 * i + 1] = *(const float4*)(src + lin + 4);
        }
      }
      f32x4 acc[2][2] = {};
      #pragma unroll
      for (int ks = 0; ks < 8; ++ks) {
        const bf8_t bbv = *(const bf8_t*)(&htile[cur][nf * 16 + col16][ks * 32 + grp * 8]);
        #pragma unroll
        for (int g = 0; g < 2; ++g) {
          acc[g][0] = __builtin_amdgcn_mfma_f32_16x16x32_bf16(afr[g][0][ks], bbv, acc[g][0], 0, 0, 0);
          acc[g][1] = __builtin_amdgcn_mfma_f32_16x16x32_bf16(afr[g][1][ks], bbv, acc[g][1], 0, 0, 0);
        }
      }
      #pragma unroll
      for (int g = 0; g < 2; ++g) {
        float ps = 0.f;
        #pragma unroll
        for (int mf = 0; mf < 2; ++mf)
          #pragma unroll
          for (int r = 0; r < 4; ++r) ps += vsv[mf][r] * fast_tanh(acc[g][mf][r]);
        ps += __shfl_xor(ps, 16);
        ps += __shfl_xor(ps, 32);
        if (lane < 16) s_part[cb][w][g][nf * 16 + lane] = ps;
      }
      if (c < 7) {
        #pragma unroll
        for (int i = 0; i < 2; ++i) {
          const int lin = (nf * 2 + i) * 2048 + tid * 8;
          const int row = lin >> 8, col = lin & 255;
          const float4 a = sv[2 * i], bsv = sv[2 * i + 1];
          bf8_t o;
          o[0] = bfbits(a.x); o[1] = bfbits(a.y); o[2] = bfbits(a.z); o[3] = bfbits(a.w);
          o[4] = bfbits(bsv.x); o[5] = bfbits(bsv.y); o[6] = bfbits(bsv.z); o[7] = bfbits(bsv.w);
          *(bf8_t*)(&htile[nxt][row][col]) = o;
        }
      }
    }
    __syncthreads();
    if (tid < 128) {
      const int g = tid >> 6, key = tid & 63;
      s_full[g][k0 + key] = s_part[cb][0][g][key] + s_part[cb][1][g][key] +
                            s_part[cb][2][g][key] + s_part[cb][3][g][key];
    }
    cur = nxt;
  }
  __syncthreads();
  float av[2][2];
  #pragma unroll
  for (int g = 0; g < 2; ++g) {
    const float s0 = s_full[g][tid], s1 = s_full[g][tid + 256];
    float m = fmaxf(s0, s1);
    #pragma unroll
    for (int d = 1; d < 64; d <<= 1) m = fmaxf(m, __shfl_xor(m, d));
    if (lane == 0) red[w] = m;
    __syncthreads();
    m = fmaxf(fmaxf(red[0], red[1]), fmaxf(red[2], red[3]));
    const float p0 = exp2f((s0 - m) * 1.44269504f);
    const float p1 = exp2f((s1 - m) * 1.44269504f);
    float sm = p0 + p1;
    #pragma unroll
    for (int d = 1; d < 64; d <<= 1) sm += __shfl_xor(sm, d);
    if (lane == 0) red[4 + w] = sm;
    __syncthreads();
    const float inv = 1.0f / (red[4] + red[5] + red[6] + red[7]);
    av[g][0] = p0 * inv; av[g][1] = p1 * inv;
    float* attp = out + (size_t)Bb * Ss * Ff + ((size_t)(b * Ss + q0 + g)) * Ss;
    attp[tid] = av[g][0];
    attp[tid + 256] = av[g][1];
    __syncthreads();
  }
  s_full[0][tid] = av[0][0]; s_full[0][tid + 256] = av[0][1];
  s_full[1][tid] = av[1][0]; s_full[1][tid + 256] = av[1][1];
  __syncthreads();
  float* ctxp = (float*)htile;
  float4 c0v = {0,0,0,0}, c1v = {0,0,0,0};
  const float* hp = Hb + (size_t)(w * 128) * Ff + lane * 4;
  #pragma unroll 8
  for (int k = 0; k < 128; ++k) {
    const float4 h = *(const float4*)(hp + (size_t)k * Ff);
    const float a0 = s_full[0][w * 128 + k];
    const float a1 = s_full[1][w * 128 + k];
    c0v.x += a0 * h.x; c0v.y += a0 * h.y; c0v.z += a0 * h.z; c0v.w += a0 * h.w;
    c1v.x += a1 * h.x; c1v.y += a1 * h.y; c1v.z += a1 * h.z; c1v.w += a1 * h.w;
  }
  *(float4*)(&ctxp[(w * 2 + 0) * 256 + lane * 4]) = c0v;
  *(float4*)(&ctxp[(w * 2 + 1) * 256 + lane * 4]) = c1v;
  __syncthreads();
  #pragma unroll
  for (int rep = 0; rep < 2; ++rep) {
    const int idx = tid + rep * 256;
    const int g = idx >> 8, f = idx & 255;
    out[((size_t)(b * Ss) + q0 + g) * Ff + f] =
        ctxp[(0 * 2 + g) * 256 + f] + ctxp[(1 * 2 + g) * 256 + f] +
        ctxp[(2 * 2 + g) * 256 + f] + ctxp[(3 * 2 + g) * 256 + f];
  }
}

extern "C" void kernel_launch(void* const* d_in, const int* in_sizes, int n_in,
                              void* d_out, int out_size, void* d_ws, size_t ws_size,
                              hipStream_t stream) {
  (void)in_sizes; (void)n_in; (void)out_size;
  const float* hidden = (const float*)d_in[0];
  const float* Ws     = (const float*)d_in[1];
  const float* vs     = (const float*)d_in[2];
  float* out          = (float*)d_out;

  const size_t hbf_bytes = (size_t)Bb * Ss * Ff * sizeof(short);   // 1 MB
  const size_t sws_bytes = (size_t)Bb * Ss * Ss * sizeof(float);   // 4 MB
  if (ws_size >= hbf_bytes + sws_bytes) {
    short* hbf = (short*)d_ws;
    float* Sws = (float*)((char*)d_ws + hbf_bytes);
    cvt_kernel<<<dim3(Bb * Ss * Ff / 4 / 256), dim3(256), 0, stream>>>(hidden, hbf);
    score_kernel<<<dim3(Bb * Ss / 2), dim3(256), 0, stream>>>(hidden, hbf, Ws, vs, Sws);
    ctx_kernel<<<dim3(Bb * Ss / 4), dim3(256), 0, stream>>>(hidden, Sws, out);
  } else {
    selfatten_fallback<<<dim3(Bb * Ss / 2), dim3(256), 0, stream>>>(hidden, Ws, vs, out);
  }
}